// Round 2
// baseline (494.334 us; speedup 1.0000x reference)
//
#include <hip/hip_runtime.h>
#include <math.h>

// CurvatureGatedGCN: out = L2( relu( L1(x) ) )
// Algebra: both convs are linear in the aggregated features, so aggregate
// first (cheap per-edge work), then one tiny per-node GEMM:
//   L(v)[c] = aggG[c] @ Wh + bh + aggS[c] @ Wt + sw[c]*bt
//   aggG[c] = sum_{e: col=c} norm_e * v[row_e] + dinv[c]^2 * v[c]
//   aggS[c] = sum_{e: col=c} ghet_e * |v[c]-v[row_e]|
//   sw[c]   = sum ghet_e
//   norm_e  = dinv[r]*g_e*dinv[c];  g_e = sigmoid(curv/5); ghet_e = 1-g_e
//   deg[c]  = 1 + sum_{e: col=c} g_e  (layer-independent)

#define D 64

__global__ void k_init(float* degw, int* cnt, int n) {
  int i = blockIdx.x * blockDim.x + threadIdx.x;
  if (i < n) { degw[i] = 1.0f; cnt[i] = 0; }
}

__global__ void k_hist(const int* __restrict__ col, const float* __restrict__ curv,
                       int* __restrict__ cnt, float* __restrict__ degw, int E) {
  int e = blockIdx.x * blockDim.x + threadIdx.x;
  if (e >= E) return;
  int c = col[e];
  float g = 1.0f / (1.0f + expf(-curv[e] * 0.2f));
  atomicAdd(&cnt[c], 1);
  atomicAdd(&degw[c], g);
}

// ---- 3-phase exclusive scan (n <= 256*256) ----
__global__ void k_scanA(const int* __restrict__ cnt, int* __restrict__ part,
                        int* __restrict__ bsum, int n) {
  __shared__ int tmp[256];
  int tid = threadIdx.x;
  int gid = blockIdx.x * 256 + tid;
  int v = (gid < n) ? cnt[gid] : 0;
  tmp[tid] = v;
  __syncthreads();
  for (int off = 1; off < 256; off <<= 1) {
    int t = (tid >= off) ? tmp[tid - off] : 0;
    __syncthreads();
    tmp[tid] += t;
    __syncthreads();
  }
  if (gid < n) part[gid] = tmp[tid] - v;
  if (tid == 255) bsum[blockIdx.x] = tmp[255];
}

__global__ void k_scanB(int* __restrict__ bsum, int nb) {
  __shared__ int tmp[256];
  int tid = threadIdx.x;
  int v = (tid < nb) ? bsum[tid] : 0;
  tmp[tid] = v;
  __syncthreads();
  for (int off = 1; off < 256; off <<= 1) {
    int t = (tid >= off) ? tmp[tid - off] : 0;
    __syncthreads();
    tmp[tid] += t;
    __syncthreads();
  }
  if (tid < nb) bsum[tid] = tmp[tid] - v;
}

__global__ void k_scanC(const int* __restrict__ part, const int* __restrict__ bsum,
                        const float* __restrict__ degw,
                        int* __restrict__ ptr, int* __restrict__ cursor,
                        float* __restrict__ dinv, int n, int E) {
  int gid = blockIdx.x * 256 + threadIdx.x;
  if (gid < n) {
    int p = part[gid] + bsum[gid >> 8];
    ptr[gid] = p;
    cursor[gid] = p;
    dinv[gid] = 1.0f / sqrtf(degw[gid]);   // degw >= 1 always
  }
  if (gid == 0) ptr[n] = E;
}

__global__ void k_fill(const int* __restrict__ row, const int* __restrict__ col,
                       const float* __restrict__ curv, const float* __restrict__ dinv,
                       int* __restrict__ cursor, int4* __restrict__ meta, int E) {
  int e = blockIdx.x * blockDim.x + threadIdx.x;
  if (e >= E) return;
  int c = col[e];
  int r = row[e];
  float g = 1.0f / (1.0f + expf(-curv[e] * 0.2f));
  int pos = atomicAdd(&cursor[c], 1);
  meta[pos] = make_int4(r, __float_as_int(dinv[r] * g * dinv[c]),
                        __float_as_int(1.0f - g), 0);
}

__device__ inline float rlane(float v, int k) {
  return __int_as_float(__builtin_amdgcn_readlane(__float_as_int(v), k));
}

// Fused layer: CSR pull aggregation + per-node [1,64]@[64,64]x2 epilogue.
// 1 wave per node, lane = output feature. ZERO LDS: W columns live in VGPRs
// (static-index arrays), cross-lane broadcast via v_readlane (VALU pipe),
// so the per-CU LDS pipe is never the serializer.
__global__ __launch_bounds__(256) void k_layer(
    const float* __restrict__ v, const int* __restrict__ ptr,
    const int4* __restrict__ meta, const float* __restrict__ dinv,
    const float* __restrict__ Wh, const float* __restrict__ bh,
    const float* __restrict__ Wt, const float* __restrict__ bt,
    float* __restrict__ out, int n, int do_relu) {
  int tid = threadIdx.x;
  int wid = tid >> 6, lane = tid & 63;

  // Per-lane W columns: wh[k] = Wh[k][lane]. Coalesced; L2-resident (32KB
  // shared by all waves). Static indices -> stays in VGPRs (128 regs).
  float wh[64], wt[64];
#pragma unroll
  for (int k = 0; k < 64; ++k) wh[k] = Wh[k * D + lane];
#pragma unroll
  for (int k = 0; k < 64; ++k) wt[k] = Wt[k * D + lane];
  float bhl = bh[lane], btl = bt[lane];

  for (int c = blockIdx.x * 4 + wid; c < n; c += gridDim.x * 4) {
    float vc = v[(size_t)c * D + lane];
    float dc = dinv[c];
    float accG = dc * dc * vc;        // GCN self-loop term
    float accS = 0.0f, sw = 0.0f;
    int s = ptr[c], e = ptr[c + 1];
#pragma unroll 4
    for (int i = s; i < e; ++i) {
      int4 m = meta[i];               // one 16B load: {row, norm, ghet, -}
      float vr = v[(size_t)m.x * D + lane];
      float nrm = __int_as_float(m.y);
      float gh  = __int_as_float(m.z);
      accG = fmaf(nrm, vr, accG);
      accS = fmaf(gh, fabsf(vc - vr), accS);
      sw += gh;
    }

    // epilogue GEMM: o[lane] = bh + sw*bt + sum_k accG[k]*Wh[k][lane]
    //                                     + sum_k accS[k]*Wt[k][lane]
    // readlane broadcast (no LDS); 4 partial sums break the FMA chain.
    float o0 = bhl + sw * btl;
    float o1 = 0.0f, o2 = 0.0f, o3 = 0.0f;
#pragma unroll
    for (int k = 0; k < 64; k += 2) {
      float g0 = rlane(accG, k),     s0 = rlane(accS, k);
      float g1 = rlane(accG, k + 1), s1 = rlane(accS, k + 1);
      o0 = fmaf(g0, wh[k], o0);
      o1 = fmaf(s0, wt[k], o1);
      o2 = fmaf(g1, wh[k + 1], o2);
      o3 = fmaf(s1, wt[k + 1], o3);
    }
    float o = (o0 + o1) + (o2 + o3);
    if (do_relu) o = fmaxf(o, 0.0f);
    out[(size_t)c * D + lane] = o;
  }
}

extern "C" void kernel_launch(void* const* d_in, const int* in_sizes, int n_in,
                              void* d_out, int out_size, void* d_ws, size_t ws_size,
                              hipStream_t stream) {
  const float* x    = (const float*)d_in[0];
  const int*   ei   = (const int*)d_in[1];
  const float* curv = (const float*)d_in[2];
  const float* Wh1  = (const float*)d_in[3];
  const float* bh1  = (const float*)d_in[4];
  const float* Wh2  = (const float*)d_in[5];
  const float* bh2  = (const float*)d_in[6];
  const float* Wt1  = (const float*)d_in[7];
  const float* bt1  = (const float*)d_in[8];
  const float* Wt2  = (const float*)d_in[9];
  const float* bt2  = (const float*)d_in[10];

  int n = in_sizes[0] / D;
  int E = in_sizes[2];
  const int* row = ei;
  const int* col = ei + E;
  float* out = (float*)d_out;

  char* w = (char*)d_ws;
  auto carve = [&](size_t bytes) {
    char* p = w;
    w += (bytes + 255) & ~(size_t)255;
    return (void*)p;
  };
  float* degw   = (float*)carve((size_t)n * 4);
  float* dinv   = (float*)carve((size_t)n * 4);
  int*   cnt    = (int*)carve((size_t)n * 4);
  int*   part   = (int*)carve((size_t)n * 4);
  int*   ptr    = (int*)carve((size_t)(n + 1) * 4);
  int*   cursor = (int*)carve((size_t)n * 4);
  int*   bsum   = (int*)carve(256 * 4);
  int4*  meta   = (int4*)carve((size_t)E * 16);
  float* h      = (float*)carve((size_t)n * D * 4);

  int nbN = (n + 255) / 256;
  int nbE = (E + 255) / 256;

  k_init<<<nbN, 256, 0, stream>>>(degw, cnt, n);
  k_hist<<<nbE, 256, 0, stream>>>(col, curv, cnt, degw, E);
  k_scanA<<<nbN, 256, 0, stream>>>(cnt, part, bsum, n);
  k_scanB<<<1, 256, 0, stream>>>(bsum, nbN);
  k_scanC<<<nbN, 256, 0, stream>>>(part, bsum, degw, ptr, cursor, dinv, n, E);
  k_fill<<<nbE, 256, 0, stream>>>(row, col, curv, dinv, cursor, meta, E);

  k_layer<<<1024, 256, 0, stream>>>(x, ptr, meta, dinv,
                                    Wh1, bh1, Wt1, bt1, h, n, 1);
  k_layer<<<1024, 256, 0, stream>>>(h, ptr, meta, dinv,
                                    Wh2, bh2, Wt2, bt2, out, n, 0);
}

// Round 7
// 429.389 us; speedup vs baseline: 1.1512x; 1.1512x over previous
//
#include <hip/hip_runtime.h>
#include <math.h>

// CurvatureGatedGCN: out = L2( relu( L1(x) ) )
// Algebra: both convs are linear in the aggregated features -> aggregate
// first, then one tiny per-node GEMM:
//   L(v)[c] = aggG[c] @ Wh + bh + aggS[c] @ Wt + sw[c]*bt
//   aggG[c] = sum_{e: col=c} norm_e * v[row_e] + dinv[c]^2 * v[c]
//   aggS[c] = sum_{e: col=c} ghet_e * |v[c]-v[row_e]|
//   sw[c]   = sum ghet_e
//   norm_e  = dinv[r]*g_e*dinv[c];  g_e = sigmoid(curv/5); ghet_e = 1-g_e
//   deg[c]  = 1 + sum_{e: col=c} g_e  (layer-independent)

#define D 64

typedef int iv4 __attribute__((ext_vector_type(4)));   // native vector: NT-loadable

__global__ void k_hist(const int* __restrict__ col, const float* __restrict__ curv,
                       int* __restrict__ cnt, float* __restrict__ degw,
                       float* __restrict__ gbuf, int E) {
  int e = blockIdx.x * blockDim.x + threadIdx.x;
  if (e >= E) return;
  int c = col[e];
  float g = 1.0f / (1.0f + expf(-curv[e] * 0.2f));
  gbuf[e] = g;                       // cache gate: k_fill reuses (no 2nd expf)
  atomicAdd(&cnt[c], 1);
  atomicAdd(&degw[c], g);
}

// ---- 3-phase exclusive scan (n <= 256*256) ----
__global__ void k_scanA(const int* __restrict__ cnt, int* __restrict__ part,
                        int* __restrict__ bsum, int n) {
  __shared__ int tmp[256];
  int tid = threadIdx.x;
  int gid = blockIdx.x * 256 + tid;
  int v = (gid < n) ? cnt[gid] : 0;
  tmp[tid] = v;
  __syncthreads();
  for (int off = 1; off < 256; off <<= 1) {
    int t = (tid >= off) ? tmp[tid - off] : 0;
    __syncthreads();
    tmp[tid] += t;
    __syncthreads();
  }
  if (gid < n) part[gid] = tmp[tid] - v;
  if (tid == 255) bsum[blockIdx.x] = tmp[255];
}

__global__ void k_scanB(int* __restrict__ bsum, int nb) {
  __shared__ int tmp[256];
  int tid = threadIdx.x;
  int v = (tid < nb) ? bsum[tid] : 0;
  tmp[tid] = v;
  __syncthreads();
  for (int off = 1; off < 256; off <<= 1) {
    int t = (tid >= off) ? tmp[tid - off] : 0;
    __syncthreads();
    tmp[tid] += t;
    __syncthreads();
  }
  if (tid < nb) bsum[tid] = tmp[tid] - v;
}

__global__ void k_scanC(const int* __restrict__ part, const int* __restrict__ bsum,
                        const float* __restrict__ degw,
                        int* __restrict__ ptr, int* __restrict__ cursor,
                        float* __restrict__ dinv, int n, int E) {
  int gid = blockIdx.x * 256 + threadIdx.x;
  if (gid < n) {
    int p = part[gid] + bsum[gid >> 8];
    ptr[gid] = p;
    cursor[gid] = p;
    dinv[gid] = rsqrtf(1.0f + degw[gid]);   // deg = 1 + sum(g) >= 1
  }
  if (gid == 0) ptr[n] = E;
}

__global__ void k_fill(const int* __restrict__ row, const int* __restrict__ col,
                       const float* __restrict__ gbuf, const float* __restrict__ dinv,
                       int* __restrict__ cursor, iv4* __restrict__ meta, int E) {
  int e = blockIdx.x * blockDim.x + threadIdx.x;
  if (e >= E) return;
  int c = col[e];
  int r = row[e];
  float g = gbuf[e];
  int pos = atomicAdd(&cursor[c], 1);
  iv4 m;
  m.x = r;
  m.y = __float_as_int(dinv[r] * g * dinv[c]);
  m.z = __float_as_int(1.0f - g);
  m.w = 0;
  meta[pos] = m;
}

__device__ inline float rlane(float v, int k) {
  return __int_as_float(__builtin_amdgcn_readlane(__float_as_int(v), k));
}

// Aggregation: one node per wave, lane = feature. Low VGPR -> max occupancy
// for latency hiding; unroll-8 keeps 8 independent gather chains in flight.
// meta[] is a 16MB once-per-layer stream -> nontemporal, so it doesn't evict
// the feature table v[] (12.8MB, reused ~20x) from L2.
__global__ __launch_bounds__(256) void k_agg(
    const float* __restrict__ v, const int* __restrict__ ptr,
    const iv4* __restrict__ meta, const float* __restrict__ dinv,
    float* __restrict__ aggG, float* __restrict__ aggS,
    float* __restrict__ swv, int n) {
  int wid = __builtin_amdgcn_readfirstlane(threadIdx.x >> 6);
  int lane = threadIdx.x & 63;
  int c = blockIdx.x * 4 + wid;
  if (c >= n) return;

  float vc = v[(size_t)c * D + lane];
  float dc = dinv[c];
  float accG = dc * dc * vc;        // GCN self-loop term
  float accS = 0.0f, sw = 0.0f;
  int s = ptr[c], e = ptr[c + 1];

  int i = s;
#pragma unroll 1
  for (; i + 8 <= e; i += 8) {
    iv4 m[8];
    float vr[8];
#pragma unroll
    for (int u = 0; u < 8; ++u) m[u] = __builtin_nontemporal_load(&meta[i + u]);
#pragma unroll
    for (int u = 0; u < 8; ++u) vr[u] = v[(size_t)m[u].x * D + lane];
#pragma unroll
    for (int u = 0; u < 8; ++u) {
      float nrm = __int_as_float(m[u].y);
      float gh  = __int_as_float(m[u].z);
      accG = fmaf(nrm, vr[u], accG);
      accS = fmaf(gh, fabsf(vc - vr[u]), accS);
      sw += gh;
    }
  }
  for (; i < e; ++i) {
    iv4 m = __builtin_nontemporal_load(&meta[i]);
    float vr = v[(size_t)m.x * D + lane];
    float nrm = __int_as_float(m.y);
    float gh  = __int_as_float(m.z);
    accG = fmaf(nrm, vr, accG);
    accS = fmaf(gh, fabsf(vc - vr), accS);
    sw += gh;
  }

  aggG[(size_t)c * D + lane] = accG;
  aggS[(size_t)c * D + lane] = accS;
  if (lane == 0) swv[c] = sw;
}

// Epilogue GEMM: o[node][lane] = bh + sw*bt + sum_k aggG[k]*Wh[k][lane]
//                                          + sum_k aggS[k]*Wt[k][lane]
// W staged in LDS once per block; 8 nodes per wave amortize each W read
// (ds_read_b32, 2-lanes/bank = free). Broadcast via v_readlane (VALU pipe).
__global__ __launch_bounds__(256) void k_mlp(
    const float* __restrict__ aggG, const float* __restrict__ aggS,
    const float* __restrict__ swv,
    const float* __restrict__ Wh, const float* __restrict__ bh,
    const float* __restrict__ Wt, const float* __restrict__ bt,
    float* __restrict__ out, int n, int do_relu) {
  __shared__ float WhL[64 * 64];
  __shared__ float WtL[64 * 64];
  int tid = threadIdx.x;
  for (int i = tid; i < 64 * 64 / 4; i += 256) {
    ((float4*)WhL)[i] = ((const float4*)Wh)[i];
    ((float4*)WtL)[i] = ((const float4*)Wt)[i];
  }
  __syncthreads();

  int wid = __builtin_amdgcn_readfirstlane(threadIdx.x >> 6);
  int lane = tid & 63;
  int base = (blockIdx.x * 4 + wid) * 8;
  if (base >= n) return;

  float bhl = bh[lane], btl = bt[lane];
  float g[8], s[8], o[8];
#pragma unroll
  for (int u = 0; u < 8; ++u) {
    int node = min(base + u, n - 1);
    g[u] = aggG[(size_t)node * D + lane];
    s[u] = aggS[(size_t)node * D + lane];
    o[u] = fmaf(swv[node], btl, bhl);
  }

#pragma unroll
  for (int k = 0; k < 64; ++k) {
    float wh = WhL[k * 64 + lane];
    float wt = WtL[k * 64 + lane];
#pragma unroll
    for (int u = 0; u < 8; ++u) {
      o[u] = fmaf(rlane(g[u], k), wh, o[u]);
      o[u] = fmaf(rlane(s[u], k), wt, o[u]);
    }
  }

#pragma unroll
  for (int u = 0; u < 8; ++u) {
    if (base + u < n) {
      float val = o[u];
      if (do_relu) val = fmaxf(val, 0.0f);
      out[(size_t)(base + u) * D + lane] = val;
    }
  }
}

extern "C" void kernel_launch(void* const* d_in, const int* in_sizes, int n_in,
                              void* d_out, int out_size, void* d_ws, size_t ws_size,
                              hipStream_t stream) {
  const float* x    = (const float*)d_in[0];
  const int*   ei   = (const int*)d_in[1];
  const float* curv = (const float*)d_in[2];
  const float* Wh1  = (const float*)d_in[3];
  const float* bh1  = (const float*)d_in[4];
  const float* Wh2  = (const float*)d_in[5];
  const float* bh2  = (const float*)d_in[6];
  const float* Wt1  = (const float*)d_in[7];
  const float* bt1  = (const float*)d_in[8];
  const float* Wt2  = (const float*)d_in[9];
  const float* bt2  = (const float*)d_in[10];

  int n = in_sizes[0] / D;
  int E = in_sizes[2];
  const int* row = ei;
  const int* col = ei + E;
  float* out = (float*)d_out;

  char* w = (char*)d_ws;
  auto carve = [&](size_t bytes) {
    char* p = w;
    w += (bytes + 255) & ~(size_t)255;
    return (void*)p;
  };
  // cnt and degw adjacent -> single async memset zeroes both
  int*   cnt    = (int*)carve((size_t)n * 8);
  float* degw   = (float*)((char*)cnt + (size_t)n * 4);
  float* dinv   = (float*)carve((size_t)n * 4);
  int*   part   = (int*)carve((size_t)n * 4);
  int*   ptr    = (int*)carve((size_t)(n + 1) * 4);
  int*   cursor = (int*)carve((size_t)n * 4);
  int*   bsum   = (int*)carve(256 * 4);
  float* gbuf   = (float*)carve((size_t)E * 4);
  iv4*   meta   = (iv4*)carve((size_t)E * 16);
  float* h      = (float*)carve((size_t)n * D * 4);
  float* aggG   = (float*)carve((size_t)n * D * 4);   // reused by both layers
  float* aggS   = (float*)carve((size_t)n * D * 4);
  float* swv    = (float*)carve((size_t)n * 4);

  int nbN = (n + 255) / 256;
  int nbE = (E + 255) / 256;
  int nbA = (n + 3) / 4;        // k_agg: 1 node/wave, 4 waves/block
  int nbM = (n + 31) / 32;      // k_mlp: 8 nodes/wave, 4 waves/block

  (void)hipMemsetAsync(cnt, 0, (size_t)n * 8, stream);
  k_hist<<<nbE, 256, 0, stream>>>(col, curv, cnt, degw, gbuf, E);
  k_scanA<<<nbN, 256, 0, stream>>>(cnt, part, bsum, n);
  k_scanB<<<1, 256, 0, stream>>>(bsum, nbN);
  k_scanC<<<nbN, 256, 0, stream>>>(part, bsum, degw, ptr, cursor, dinv, n, E);
  k_fill<<<nbE, 256, 0, stream>>>(row, col, gbuf, dinv, cursor, meta, E);

  // layer 1: x -> h (relu)
  k_agg<<<nbA, 256, 0, stream>>>(x, ptr, meta, dinv, aggG, aggS, swv, n);
  k_mlp<<<nbM, 256, 0, stream>>>(aggG, aggS, swv, Wh1, bh1, Wt1, bt1, h, n, 1);
  // layer 2: h -> out
  k_agg<<<nbA, 256, 0, stream>>>(h, ptr, meta, dinv, aggG, aggS, swv, n);
  k_mlp<<<nbM, 256, 0, stream>>>(aggG, aggS, swv, Wh2, bh2, Wt2, bt2, out, n, 0);
}

// Round 8
// 340.904 us; speedup vs baseline: 1.4501x; 1.2596x over previous
//
#include <hip/hip_runtime.h>
#include <math.h>

// CurvatureGatedGCN: out = L2( relu( L1(x) ) )
// Algebra: both convs are linear in the aggregated features -> aggregate
// first, then one tiny per-node GEMM:
//   L(v)[c] = aggG[c] @ Wh + bh + aggS[c] @ Wt + sw[c]*bt
//   aggG[c] = sum_{e: col=c} norm_e * v[row_e] + dinv[c]^2 * v[c]
//   aggS[c] = sum_{e: col=c} ghet_e * |v[c]-v[row_e]|
//   sw[c]   = sum ghet_e
//   norm_e  = dinv[r]*g_e*dinv[c];  g_e = sigmoid(curv/5); ghet_e = 1-g_e
//   deg[c]  = 1 + sum_{e: col=c} g_e  (layer-independent)
//
// CSR build uses ONE u64 far-atomic per edge (R7: 3M atomics -> 1M; each
// far-atomic write-throughs a ~32B sector to HBM, measured 66MB for 2M).
// packed[c] layout: [63:45] = count, [44:0] = sum(g) in 2^-38 fixed point.
// atomicAdd's returned old count field = this edge's rank = CSR ticket.

#define D 64
#define PSHIFT 45
#define PSCALE 274877906944.0f        // 2^38
#define PMASK  ((1ull << PSHIFT) - 1)

typedef unsigned long long u64;
typedef int iv4 __attribute__((ext_vector_type(4)));   // native vector: NT-loadable

__global__ void k_phase1(const int* __restrict__ col, const float* __restrict__ curv,
                         u64* __restrict__ packed, float* __restrict__ gbuf,
                         unsigned short* __restrict__ rank, int E) {
  int e = blockIdx.x * blockDim.x + threadIdx.x;
  if (e >= E) return;
  int c = col[e];
  float g = 1.0f / (1.0f + expf(-curv[e] * 0.2f));
  gbuf[e] = g;                                   // cache gate for phase2
  u64 inc = ((u64)1 << PSHIFT) | (u64)(g * PSCALE);
  u64 old = atomicAdd(&packed[c], inc);          // ONE far-atomic per edge
  rank[e] = (unsigned short)(old >> PSHIFT);     // CSR ticket
}

// ---- 3-phase exclusive scan (n <= 256*256) ----
__global__ void k_scanA(const u64* __restrict__ packed, int* __restrict__ part,
                        int* __restrict__ bsum, int n) {
  __shared__ int tmp[256];
  int tid = threadIdx.x;
  int gid = blockIdx.x * 256 + tid;
  int v = (gid < n) ? (int)(packed[gid] >> PSHIFT) : 0;
  tmp[tid] = v;
  __syncthreads();
  for (int off = 1; off < 256; off <<= 1) {
    int t = (tid >= off) ? tmp[tid - off] : 0;
    __syncthreads();
    tmp[tid] += t;
    __syncthreads();
  }
  if (gid < n) part[gid] = tmp[tid] - v;
  if (tid == 255) bsum[blockIdx.x] = tmp[255];
}

__global__ void k_scanB(int* __restrict__ bsum, int nb) {
  __shared__ int tmp[256];
  int tid = threadIdx.x;
  int v = (tid < nb) ? bsum[tid] : 0;
  tmp[tid] = v;
  __syncthreads();
  for (int off = 1; off < 256; off <<= 1) {
    int t = (tid >= off) ? tmp[tid - off] : 0;
    __syncthreads();
    tmp[tid] += t;
    __syncthreads();
  }
  if (tid < nb) bsum[tid] = tmp[tid] - v;
}

__global__ void k_scanC(const int* __restrict__ part, const int* __restrict__ bsum,
                        const u64* __restrict__ packed,
                        int* __restrict__ ptr, float* __restrict__ dinv,
                        int n, int E) {
  int gid = blockIdx.x * 256 + threadIdx.x;
  if (gid < n) {
    ptr[gid] = part[gid] + bsum[gid >> 8];
    float degw = (float)(packed[gid] & PMASK) * (1.0f / PSCALE);
    dinv[gid] = rsqrtf(1.0f + degw);             // deg = 1 + sum(g)
  }
  if (gid == 0) ptr[n] = E;
}

// Atomic-free CSR fill: pos = ptr[col] + rank (ticket from phase1).
__global__ void k_fill(const int* __restrict__ row, const int* __restrict__ col,
                       const float* __restrict__ gbuf,
                       const unsigned short* __restrict__ rank,
                       const int* __restrict__ ptr, const float* __restrict__ dinv,
                       iv4* __restrict__ meta, int E) {
  int e = blockIdx.x * blockDim.x + threadIdx.x;
  if (e >= E) return;
  int c = col[e];
  int r = row[e];
  float g = gbuf[e];
  int pos = ptr[c] + rank[e];
  iv4 m;
  m.x = r;
  m.y = __float_as_int(dinv[r] * g * dinv[c]);
  m.z = __float_as_int(1.0f - g);
  m.w = 0;
  meta[pos] = m;
}

__device__ inline float rlane(float v, int k) {
  return __int_as_float(__builtin_amdgcn_readlane(__float_as_int(v), k));
}

// Aggregation: one node per wave, lane = feature. Low VGPR -> max occupancy
// for latency hiding; unroll-8 keeps 8 independent gather chains in flight.
// meta[] is a 16MB once-per-layer stream -> nontemporal, so it doesn't evict
// the feature table v[] (12.8MB, reused ~20x) from L2.
__global__ __launch_bounds__(256) void k_agg(
    const float* __restrict__ v, const int* __restrict__ ptr,
    const iv4* __restrict__ meta, const float* __restrict__ dinv,
    float* __restrict__ aggG, float* __restrict__ aggS,
    float* __restrict__ swv, int n) {
  int wid = __builtin_amdgcn_readfirstlane(threadIdx.x >> 6);
  int lane = threadIdx.x & 63;
  int c = blockIdx.x * 4 + wid;
  if (c >= n) return;

  float vc = v[(size_t)c * D + lane];
  float dc = dinv[c];
  float accG = dc * dc * vc;        // GCN self-loop term
  float accS = 0.0f, sw = 0.0f;
  int s = ptr[c], e = ptr[c + 1];

  int i = s;
#pragma unroll 1
  for (; i + 8 <= e; i += 8) {
    iv4 m[8];
    float vr[8];
#pragma unroll
    for (int u = 0; u < 8; ++u) m[u] = __builtin_nontemporal_load(&meta[i + u]);
#pragma unroll
    for (int u = 0; u < 8; ++u) vr[u] = v[(size_t)m[u].x * D + lane];
#pragma unroll
    for (int u = 0; u < 8; ++u) {
      float nrm = __int_as_float(m[u].y);
      float gh  = __int_as_float(m[u].z);
      accG = fmaf(nrm, vr[u], accG);
      accS = fmaf(gh, fabsf(vc - vr[u]), accS);
      sw += gh;
    }
  }
  for (; i < e; ++i) {
    iv4 m = __builtin_nontemporal_load(&meta[i]);
    float vr = v[(size_t)m.x * D + lane];
    float nrm = __int_as_float(m.y);
    float gh  = __int_as_float(m.z);
    accG = fmaf(nrm, vr, accG);
    accS = fmaf(gh, fabsf(vc - vr), accS);
    sw += gh;
  }

  aggG[(size_t)c * D + lane] = accG;
  aggS[(size_t)c * D + lane] = accS;
  if (lane == 0) swv[c] = sw;
}

// Epilogue GEMM: o[node][lane] = bh + sw*bt + sum_k aggG[k]*Wh[k][lane]
//                                          + sum_k aggS[k]*Wt[k][lane]
// W staged in LDS once per block; 8 nodes per wave amortize each W read
// (ds_read_b32, 2-lanes/bank = free). Broadcast via v_readlane (VALU pipe).
__global__ __launch_bounds__(256) void k_mlp(
    const float* __restrict__ aggG, const float* __restrict__ aggS,
    const float* __restrict__ swv,
    const float* __restrict__ Wh, const float* __restrict__ bh,
    const float* __restrict__ Wt, const float* __restrict__ bt,
    float* __restrict__ out, int n, int do_relu) {
  __shared__ float WhL[64 * 64];
  __shared__ float WtL[64 * 64];
  int tid = threadIdx.x;
  for (int i = tid; i < 64 * 64 / 4; i += 256) {
    ((float4*)WhL)[i] = ((const float4*)Wh)[i];
    ((float4*)WtL)[i] = ((const float4*)Wt)[i];
  }
  __syncthreads();

  int wid = __builtin_amdgcn_readfirstlane(threadIdx.x >> 6);
  int lane = tid & 63;
  int base = (blockIdx.x * 4 + wid) * 8;
  if (base >= n) return;

  float bhl = bh[lane], btl = bt[lane];
  float g[8], s[8], o[8];
#pragma unroll
  for (int u = 0; u < 8; ++u) {
    int node = min(base + u, n - 1);
    g[u] = aggG[(size_t)node * D + lane];
    s[u] = aggS[(size_t)node * D + lane];
    o[u] = fmaf(swv[node], btl, bhl);
  }

#pragma unroll
  for (int k = 0; k < 64; ++k) {
    float wh = WhL[k * 64 + lane];
    float wt = WtL[k * 64 + lane];
#pragma unroll
    for (int u = 0; u < 8; ++u) {
      o[u] = fmaf(rlane(g[u], k), wh, o[u]);
      o[u] = fmaf(rlane(s[u], k), wt, o[u]);
    }
  }

#pragma unroll
  for (int u = 0; u < 8; ++u) {
    if (base + u < n) {
      float val = o[u];
      if (do_relu) val = fmaxf(val, 0.0f);
      out[(size_t)(base + u) * D + lane] = val;
    }
  }
}

extern "C" void kernel_launch(void* const* d_in, const int* in_sizes, int n_in,
                              void* d_out, int out_size, void* d_ws, size_t ws_size,
                              hipStream_t stream) {
  const float* x    = (const float*)d_in[0];
  const int*   ei   = (const int*)d_in[1];
  const float* curv = (const float*)d_in[2];
  const float* Wh1  = (const float*)d_in[3];
  const float* bh1  = (const float*)d_in[4];
  const float* Wh2  = (const float*)d_in[5];
  const float* bh2  = (const float*)d_in[6];
  const float* Wt1  = (const float*)d_in[7];
  const float* bt1  = (const float*)d_in[8];
  const float* Wt2  = (const float*)d_in[9];
  const float* bt2  = (const float*)d_in[10];

  int n = in_sizes[0] / D;
  int E = in_sizes[2];
  const int* row = ei;
  const int* col = ei + E;
  float* out = (float*)d_out;

  char* w = (char*)d_ws;
  auto carve = [&](size_t bytes) {
    char* p = w;
    w += (bytes + 255) & ~(size_t)255;
    return (void*)p;
  };
  u64*   packed = (u64*)carve((size_t)n * 8);
  float* dinv   = (float*)carve((size_t)n * 4);
  int*   part   = (int*)carve((size_t)n * 4);
  int*   ptr    = (int*)carve((size_t)(n + 1) * 4);
  int*   bsum   = (int*)carve(256 * 4);
  float* gbuf   = (float*)carve((size_t)E * 4);
  unsigned short* rank = (unsigned short*)carve((size_t)E * 2);
  iv4*   meta   = (iv4*)carve((size_t)E * 16);
  float* h      = (float*)carve((size_t)n * D * 4);
  float* aggG   = (float*)carve((size_t)n * D * 4);   // reused by both layers
  float* aggS   = (float*)carve((size_t)n * D * 4);
  float* swv    = (float*)carve((size_t)n * 4);

  int nbN = (n + 255) / 256;
  int nbE = (E + 255) / 256;
  int nbA = (n + 3) / 4;        // k_agg: 1 node/wave, 4 waves/block
  int nbM = (n + 31) / 32;      // k_mlp: 8 nodes/wave, 4 waves/block

  (void)hipMemsetAsync(packed, 0, (size_t)n * 8, stream);
  k_phase1<<<nbE, 256, 0, stream>>>(col, curv, packed, gbuf, rank, E);
  k_scanA<<<nbN, 256, 0, stream>>>(packed, part, bsum, n);
  k_scanB<<<1, 256, 0, stream>>>(bsum, nbN);
  k_scanC<<<nbN, 256, 0, stream>>>(part, bsum, packed, ptr, dinv, n, E);
  k_fill<<<nbE, 256, 0, stream>>>(row, col, gbuf, rank, ptr, dinv, meta, E);

  // layer 1: x -> h (relu)
  k_agg<<<nbA, 256, 0, stream>>>(x, ptr, meta, dinv, aggG, aggS, swv, n);
  k_mlp<<<nbM, 256, 0, stream>>>(aggG, aggS, swv, Wh1, bh1, Wt1, bt1, h, n, 1);
  // layer 2: h -> out
  k_agg<<<nbA, 256, 0, stream>>>(h, ptr, meta, dinv, aggG, aggS, swv, n);
  k_mlp<<<nbM, 256, 0, stream>>>(aggG, aggS, swv, Wh2, bh2, Wt2, bt2, out, n, 0);
}

// Round 10
// 271.403 us; speedup vs baseline: 1.8214x; 1.2561x over previous
//
#include <hip/hip_runtime.h>
#include <math.h>

// CurvatureGatedGCN: out = L2( relu( L1(x) ) )
// Algebra: both convs are linear in the aggregated features -> aggregate
// first, then one tiny per-node GEMM:
//   L(v)[c] = aggG[c] @ Wh + bh + aggS[c] @ Wt + sw[c]*bt
//   aggG[c] = sum_{e: col=c} norm_e * v[row_e] + dinv[c]^2 * v[c]
//   aggS[c] = sum_{e: col=c} ghet_e * |v[c]-v[row_e]|
//   sw[c]   = sum ghet_e
//   norm_e  = dinv[r]*g_e*dinv[c];  g_e = sigmoid(curv/5); ghet_e = 1-g_e
//
// CSR build: ONE u64 far-atomic per edge (ticket in high bits, fixed-point
// weighted degree in low bits). R8: k_mlp readlane epilogue was 58us
// (VALU-hazard-bound) -> rewritten as register-blocked LDS GEMM.

#define D 64
#define PSHIFT 45
#define PSCALE 274877906944.0f        // 2^38
#define PMASK  ((1ull << PSHIFT) - 1)

typedef unsigned long long u64;
typedef int iv4 __attribute__((ext_vector_type(4)));   // native vector: NT-loadable

__global__ void k_phase1(const int* __restrict__ col, const float* __restrict__ curv,
                         u64* __restrict__ packed, float* __restrict__ gbuf,
                         unsigned short* __restrict__ rank, int E) {
  int e = blockIdx.x * blockDim.x + threadIdx.x;
  if (e >= E) return;
  int c = col[e];
  float g = 1.0f / (1.0f + expf(-curv[e] * 0.2f));
  gbuf[e] = g;                                   // cache gate for k_fill
  u64 inc = ((u64)1 << PSHIFT) | (u64)(g * PSCALE);
  u64 old = atomicAdd(&packed[c], inc);          // ONE far-atomic per edge
  rank[e] = (unsigned short)(old >> PSHIFT);     // CSR ticket
}

// ---- 3-phase exclusive scan (n <= 256*256) ----
__global__ void k_scanA(const u64* __restrict__ packed, int* __restrict__ part,
                        int* __restrict__ bsum, int n) {
  __shared__ int tmp[256];
  int tid = threadIdx.x;
  int gid = blockIdx.x * 256 + tid;
  int v = (gid < n) ? (int)(packed[gid] >> PSHIFT) : 0;
  tmp[tid] = v;
  __syncthreads();
  for (int off = 1; off < 256; off <<= 1) {
    int t = (tid >= off) ? tmp[tid - off] : 0;
    __syncthreads();
    tmp[tid] += t;
    __syncthreads();
  }
  if (gid < n) part[gid] = tmp[tid] - v;
  if (tid == 255) bsum[blockIdx.x] = tmp[255];
}

__global__ void k_scanB(int* __restrict__ bsum, int nb) {
  __shared__ int tmp[256];
  int tid = threadIdx.x;
  int v = (tid < nb) ? bsum[tid] : 0;
  tmp[tid] = v;
  __syncthreads();
  for (int off = 1; off < 256; off <<= 1) {
    int t = (tid >= off) ? tmp[tid - off] : 0;
    __syncthreads();
    tmp[tid] += t;
    __syncthreads();
  }
  if (tid < nb) bsum[tid] = tmp[tid] - v;
}

__global__ void k_scanC(const int* __restrict__ part, const int* __restrict__ bsum,
                        const u64* __restrict__ packed,
                        int* __restrict__ ptr, float* __restrict__ dinv,
                        int n, int E) {
  int gid = blockIdx.x * 256 + threadIdx.x;
  if (gid < n) {
    ptr[gid] = part[gid] + bsum[gid >> 8];
    float degw = (float)(packed[gid] & PMASK) * (1.0f / PSCALE);
    dinv[gid] = rsqrtf(1.0f + degw);             // deg = 1 + sum(g)
  }
  if (gid == 0) ptr[n] = E;
}

// Atomic-free CSR fill: pos = ptr[col] + rank (ticket from phase1).
__global__ void k_fill(const int* __restrict__ row, const int* __restrict__ col,
                       const float* __restrict__ gbuf,
                       const unsigned short* __restrict__ rank,
                       const int* __restrict__ ptr, const float* __restrict__ dinv,
                       iv4* __restrict__ meta, int E) {
  int e = blockIdx.x * blockDim.x + threadIdx.x;
  if (e >= E) return;
  int c = col[e];
  int r = row[e];
  float g = gbuf[e];
  int pos = ptr[c] + rank[e];
  iv4 m;
  m.x = r;
  m.y = __float_as_int(dinv[r] * g * dinv[c]);
  m.z = __float_as_int(1.0f - g);
  m.w = 0;
  meta[pos] = m;
}

// Aggregation: one node per wave, lane = feature. Low VGPR -> max occupancy
// for latency hiding; unroll-8 keeps 8 independent gather chains in flight.
// meta[] is a 16MB once-per-layer stream -> nontemporal (don't evict v[]).
__global__ __launch_bounds__(256) void k_agg(
    const float* __restrict__ v, const int* __restrict__ ptr,
    const iv4* __restrict__ meta, const float* __restrict__ dinv,
    float* __restrict__ aggG, float* __restrict__ aggS,
    float* __restrict__ swv, int n) {
  int wid = __builtin_amdgcn_readfirstlane(threadIdx.x >> 6);
  int lane = threadIdx.x & 63;
  int c = blockIdx.x * 4 + wid;
  if (c >= n) return;

  float vc = v[(size_t)c * D + lane];
  float dc = dinv[c];
  float accG = dc * dc * vc;        // GCN self-loop term
  float accS = 0.0f, sw = 0.0f;
  int s = ptr[c], e = ptr[c + 1];

  int i = s;
#pragma unroll 1
  for (; i + 8 <= e; i += 8) {
    iv4 m[8];
    float vr[8];
#pragma unroll
    for (int u = 0; u < 8; ++u) m[u] = __builtin_nontemporal_load(&meta[i + u]);
#pragma unroll
    for (int u = 0; u < 8; ++u) vr[u] = v[(size_t)m[u].x * D + lane];
#pragma unroll
    for (int u = 0; u < 8; ++u) {
      float nrm = __int_as_float(m[u].y);
      float gh  = __int_as_float(m[u].z);
      accG = fmaf(nrm, vr[u], accG);
      accS = fmaf(gh, fabsf(vc - vr[u]), accS);
      sw += gh;
    }
  }
  for (; i < e; ++i) {
    iv4 m = __builtin_nontemporal_load(&meta[i]);
    float vr = v[(size_t)m.x * D + lane];
    float nrm = __int_as_float(m.y);
    float gh  = __int_as_float(m.z);
    accG = fmaf(nrm, vr, accG);
    accS = fmaf(gh, fabsf(vc - vr), accS);
    sw += gh;
  }

  aggG[(size_t)c * D + lane] = accG;
  aggS[(size_t)c * D + lane] = accS;
  if (lane == 0) swv[c] = sw;
}

// Epilogue as register-blocked LDS GEMM (R8 fix: no v_readlane).
// Block = 64-node x 64-out tile; C = [A_G|A_S][64x128] @ [Wh;Wt][128x64].
// K processed in two 64-halves reusing the same LDS buffers.
// Thread = 4x4 micro-tile; all LDS reads are ds_read_b128.
#define AP4 17   // A row stride in float4 (68 floats: pad -> 2-way banks max)
#define FMA4(i, j)                                         \
  acc[i][0] = fmaf(a4[i].j, w4j.x, acc[i][0]);             \
  acc[i][1] = fmaf(a4[i].j, w4j.y, acc[i][1]);             \
  acc[i][2] = fmaf(a4[i].j, w4j.z, acc[i][2]);             \
  acc[i][3] = fmaf(a4[i].j, w4j.w, acc[i][3]);

__global__ __launch_bounds__(256) void k_mlp(
    const float* __restrict__ aggG, const float* __restrict__ aggS,
    const float* __restrict__ swv,
    const float* __restrict__ Wh, const float* __restrict__ bh,
    const float* __restrict__ Wt, const float* __restrict__ bt,
    float* __restrict__ out, int n, int do_relu) {
  __shared__ float As[64 * 68];     // [node][k-half] padded
  __shared__ float Ws[64 * 64];     // [k-half][col]
  int tid = threadIdx.x;
  int tx = tid & 15, ty = tid >> 4;  // tx: 4-col group, ty: 4-node group
  int base = blockIdx.x * 64;

  float acc[4][4] = {{0.f}};
  const float* aggX = aggG;
  const float* Wx = Wh;

  for (int half = 0; half < 2; ++half) {
    // stage W half (4096 floats) and A half (64 nodes x 64 k), coalesced f4
#pragma unroll
    for (int j = 0; j < 4; ++j) {
      int idx = tid + j * 256;
      ((float4*)Ws)[idx] = ((const float4*)Wx)[idx];
    }
#pragma unroll
    for (int j = 0; j < 4; ++j) {
      int idx = tid + j * 256;           // 0..1023
      int nl = idx >> 4, kk = idx & 15;
      int gn = min(base + nl, n - 1);
      ((float4*)As)[nl * AP4 + kk] = ((const float4*)aggX)[(size_t)gn * 16 + kk];
    }
    __syncthreads();

#pragma unroll
    for (int kk4 = 0; kk4 < 16; ++kk4) {
      float4 a4[4];
#pragma unroll
      for (int i = 0; i < 4; ++i)
        a4[i] = ((const float4*)As)[(4 * ty + i) * AP4 + kk4];
      {
        float4 w4j = ((const float4*)Ws)[(kk4 * 4 + 0) * 16 + tx];
        FMA4(0, x) FMA4(1, x) FMA4(2, x) FMA4(3, x)
      }
      {
        float4 w4j = ((const float4*)Ws)[(kk4 * 4 + 1) * 16 + tx];
        FMA4(0, y) FMA4(1, y) FMA4(2, y) FMA4(3, y)
      }
      {
        float4 w4j = ((const float4*)Ws)[(kk4 * 4 + 2) * 16 + tx];
        FMA4(0, z) FMA4(1, z) FMA4(2, z) FMA4(3, z)
      }
      {
        float4 w4j = ((const float4*)Ws)[(kk4 * 4 + 3) * 16 + tx];
        FMA4(0, w) FMA4(1, w) FMA4(2, w) FMA4(3, w)
      }
    }
    __syncthreads();
    aggX = aggS;
    Wx = Wt;
  }

  // bias + gate-weighted bias + relu, f4 store
  float4 bh4 = ((const float4*)bh)[tx];
  float4 bt4 = ((const float4*)bt)[tx];
#pragma unroll
  for (int i = 0; i < 4; ++i) {
    int node = base + 4 * ty + i;
    if (node < n) {
      float s = swv[node];
      float4 r;
      r.x = fmaf(s, bt4.x, acc[i][0] + bh4.x);
      r.y = fmaf(s, bt4.y, acc[i][1] + bh4.y);
      r.z = fmaf(s, bt4.z, acc[i][2] + bh4.z);
      r.w = fmaf(s, bt4.w, acc[i][3] + bh4.w);
      if (do_relu) {
        r.x = fmaxf(r.x, 0.f); r.y = fmaxf(r.y, 0.f);
        r.z = fmaxf(r.z, 0.f); r.w = fmaxf(r.w, 0.f);
      }
      ((float4*)out)[(size_t)node * 16 + tx] = r;
    }
  }
}

extern "C" void kernel_launch(void* const* d_in, const int* in_sizes, int n_in,
                              void* d_out, int out_size, void* d_ws, size_t ws_size,
                              hipStream_t stream) {
  const float* x    = (const float*)d_in[0];
  const int*   ei   = (const int*)d_in[1];
  const float* curv = (const float*)d_in[2];
  const float* Wh1  = (const float*)d_in[3];
  const float* bh1  = (const float*)d_in[4];
  const float* Wh2  = (const float*)d_in[5];
  const float* bh2  = (const float*)d_in[6];
  const float* Wt1  = (const float*)d_in[7];
  const float* bt1  = (const float*)d_in[8];
  const float* Wt2  = (const float*)d_in[9];
  const float* bt2  = (const float*)d_in[10];

  int n = in_sizes[0] / D;
  int E = in_sizes[2];
  const int* row = ei;
  const int* col = ei + E;
  float* out = (float*)d_out;

  char* w = (char*)d_ws;
  auto carve = [&](size_t bytes) {
    char* p = w;
    w += (bytes + 255) & ~(size_t)255;
    return (void*)p;
  };
  u64*   packed = (u64*)carve((size_t)n * 8);
  float* dinv   = (float*)carve((size_t)n * 4);
  int*   part   = (int*)carve((size_t)n * 4);
  int*   ptr    = (int*)carve((size_t)(n + 1) * 4);
  int*   bsum   = (int*)carve(256 * 4);
  float* gbuf   = (float*)carve((size_t)E * 4);
  unsigned short* rank = (unsigned short*)carve((size_t)E * 2);
  iv4*   meta   = (iv4*)carve((size_t)E * 16);
  float* h      = (float*)carve((size_t)n * D * 4);
  float* aggG   = (float*)carve((size_t)n * D * 4);   // reused by both layers
  float* aggS   = (float*)carve((size_t)n * D * 4);
  float* swv    = (float*)carve((size_t)n * 4);

  int nbN = (n + 255) / 256;
  int nbE = (E + 255) / 256;
  int nbA = (n + 3) / 4;        // k_agg: 1 node/wave, 4 waves/block
  int nbM = (n + 63) / 64;      // k_mlp: 64-node tile per block

  (void)hipMemsetAsync(packed, 0, (size_t)n * 8, stream);
  k_phase1<<<nbE, 256, 0, stream>>>(col, curv, packed, gbuf, rank, E);
  k_scanA<<<nbN, 256, 0, stream>>>(packed, part, bsum, n);
  k_scanB<<<1, 256, 0, stream>>>(bsum, nbN);
  k_scanC<<<nbN, 256, 0, stream>>>(part, bsum, packed, ptr, dinv, n, E);
  k_fill<<<nbE, 256, 0, stream>>>(row, col, gbuf, rank, ptr, dinv, meta, E);

  // layer 1: x -> h (relu)
  k_agg<<<nbA, 256, 0, stream>>>(x, ptr, meta, dinv, aggG, aggS, swv, n);
  k_mlp<<<nbM, 256, 0, stream>>>(aggG, aggS, swv, Wh1, bh1, Wt1, bt1, h, n, 1);
  // layer 2: h -> out
  k_agg<<<nbA, 256, 0, stream>>>(h, ptr, meta, dinv, aggG, aggS, swv, n);
  k_mlp<<<nbM, 256, 0, stream>>>(aggG, aggS, swv, Wh2, bh2, Wt2, bt2, out, n, 0);
}